// Round 1
// 324.083 us; speedup vs baseline: 1.1413x; 1.1413x over previous
//
#include <hip/hip_runtime.h>

// GCNEncoder: 2x GCNConv(64->64) + BatchNorm + ELU + global_mean_pool
// N=50000, E=800000, D=64, G=64. Inputs f32/int32, output f32.
// R13 844.7 -> R14 571.1 (kill hist contention) -> R15 675.7 (bad gather
// launch shape) -> R16 451.2 (1 wave/row gather + shfl staging) ->
// R17 366.7 (hierarchical 3-pass scan, dinv fused).
// R17 profile: gather 57us x2, latency-bound (VALUBusy 19%, HBM 21%, L2 ~3.6TB/s).
// R18: gather lanes reshaped to 4 neighbor-slots x 16 channel-quads:
//   float4 loads (4 rows in flight per instr), 4x fewer loads+bpermutes,
//   butterfly-reduce over slots, coalesced float4 store.

constexpr int GGRAPHS = 64;

__global__ void deg_kernel(const int* __restrict__ dst, int* __restrict__ deg, int E, int n) {
  int i = blockIdx.x * 256 + threadIdx.x;
  if (i < E) {
    int d = dst[i];
    if ((unsigned)d < (unsigned)n) atomicAdd(&deg[d], 1);
  }
}

// cnt[g] via per-block LDS histogram (batch sorted -> storms stay in LDS)
__global__ void cnt_kernel(const int* __restrict__ batch, int* __restrict__ cnt, int n) {
  __shared__ int h[GGRAPHS];
  int t = threadIdx.x;
  if (t < GGRAPHS) h[t] = 0;
  __syncthreads();
  for (int i = blockIdx.x * 256 + t; i < n; i += gridDim.x * 256) {
    int g = batch[i];
    if ((unsigned)g < (unsigned)GGRAPHS) atomicAdd(&h[g], 1);
  }
  __syncthreads();
  if (t < GGRAPHS && h[t] > 0) atomicAdd(&cnt[t], h[t]);
}

// scan pass 1: per-256-tile exclusive scan (Hillis-Steele in LDS);
// rowptr[i] = local exclusive sum; bsum[b] = tile total.
__global__ void scan1_kernel(const int* __restrict__ deg, int* __restrict__ rowptr,
                             int* __restrict__ bsum, int n) {
  __shared__ int tmp[256];
  int t = threadIdx.x;
  int i = blockIdx.x * 256 + t;
  int v = (i < n) ? deg[i] : 0;
  tmp[t] = v;
  __syncthreads();
#pragma unroll
  for (int off = 1; off < 256; off <<= 1) {
    int a = (t >= off) ? tmp[t - off] : 0;
    __syncthreads();
    tmp[t] += a;
    __syncthreads();
  }
  if (i < n) rowptr[i] = tmp[t] - v;  // exclusive
  if (t == 255) bsum[blockIdx.x] = tmp[255];
}

// scan pass 2: 1 block, exclusive scan of bsum[nb] (nb <= 256); bsum[nb] = total.
__global__ void scan2_kernel(int* __restrict__ bsum, int nb) {
  __shared__ int tmp[256];
  int t = threadIdx.x;
  int v = (t < nb) ? bsum[t] : 0;
  tmp[t] = v;
  __syncthreads();
#pragma unroll
  for (int off = 1; off < 256; off <<= 1) {
    int a = (t >= off) ? tmp[t - off] : 0;
    __syncthreads();
    tmp[t] += a;
    __syncthreads();
  }
  if (t < nb) bsum[t] = tmp[t] - v;
  if (t == 255) bsum[nb] = tmp[255];
}

// scan pass 3: rowptr[i] += bsum[block]; fused dinv = rsqrt(deg+1); rowptr[n] = total.
__global__ void scan3_kernel(const int* __restrict__ deg, int* __restrict__ rowptr,
                             const int* __restrict__ bsum, float* __restrict__ dinv,
                             int n, int nb) {
  int i = blockIdx.x * 256 + threadIdx.x;
  if (i < n) {
    rowptr[i] += bsum[blockIdx.x];
    dinv[i] = rsqrtf((float)deg[i] + 1.0f);
  }
  if (i == 0) rowptr[n] = bsum[nb];
}

__global__ void fill_kernel(const int* __restrict__ srcp, const int* __restrict__ dstp,
                            const int* __restrict__ rowptr, int* __restrict__ slot,
                            int* __restrict__ col, int E, int n) {
  int e = blockIdx.x * 256 + threadIdx.x;
  if (e >= E) return;
  int s = srcp[e], d = dstp[e];
  if ((unsigned)s >= (unsigned)n || (unsigned)d >= (unsigned)n) return;
  int pos = rowptr[d] + atomicAdd(&slot[d], 1);
  col[pos] = s;
}

// Y[n,64] = X[n,64] @ W[64,64]; block = 4 rows x 64 cols
__global__ void mm64_kernel(const float* __restrict__ X, const float* __restrict__ W,
                            float* __restrict__ Y, int n) {
  __shared__ float Ws[64][64];
  __shared__ float xs[4][64];
  int tid = threadIdx.x;
  for (int i = tid; i < 64 * 64; i += 256) Ws[i >> 6][i & 63] = W[i];
  int rr = tid >> 6, c = tid & 63;
  int row = blockIdx.x * 4 + rr;
  xs[rr][c] = (row < n) ? X[row * 64 + c] : 0.0f;
  __syncthreads();
  float acc = 0.0f;
#pragma unroll
  for (int k = 0; k < 64; ++k) acc = fmaf(xs[rr][k], Ws[k][c], acc);
  if (row < n) Y[row * 64 + c] = acc;
}

// BN affine + ELU on X rows, then @W
__global__ void bn_elu_mm64_kernel(const float* __restrict__ X, const float* __restrict__ W,
                                   const float* __restrict__ ss, float* __restrict__ Y, int n) {
  __shared__ float Ws[64][64];
  __shared__ float xs[4][64];
  int tid = threadIdx.x;
  for (int i = tid; i < 64 * 64; i += 256) Ws[i >> 6][i & 63] = W[i];
  int rr = tid >> 6, c = tid & 63;
  int row = blockIdx.x * 4 + rr;
  float v = 0.0f;
  if (row < n) {
    v = X[row * 64 + c] * ss[c] + ss[64 + c];
    v = v > 0.0f ? v : expm1f(v);
  }
  xs[rr][c] = v;
  __syncthreads();
  float acc = 0.0f;
#pragma unroll
  for (int k = 0; k < 64; ++k) acc = fmaf(xs[rr][k], Ws[k][c], acc);
  if (row < n) Y[row * 64 + c] = acc;
}

// CSR gather, 1 wave per row. Lanes = 4 neighbor-slots x 16 channel-quads:
// each lane float4-loads 4 channels of one of 4 concurrent neighbor rows.
// Staged col/dinv chunks (64 at a time) broadcast via ds_bpermute (1 pair
// per 4 neighbors). Butterfly-reduce slots at the end; sub0 stores float4.
__global__ void gather_kernel(const int* __restrict__ rowptr, const int* __restrict__ col,
                              const float* __restrict__ dinv, const float* __restrict__ H,
                              const float* __restrict__ b, float* __restrict__ OUT, int n) {
  int wave = threadIdx.x >> 6;
  int lane = threadIdx.x & 63;
  int row = blockIdx.x * 4 + wave;
  if (row >= n) return;
  int sub = lane >> 4;   // neighbor slot 0..3
  int cg = lane & 15;    // channel quad: channels 4*cg .. 4*cg+3
  int p0 = rowptr[row], p1 = rowptr[row + 1];
  const float4* __restrict__ H4 = (const float4*)H;
  float4 acc = make_float4(0.0f, 0.0f, 0.0f, 0.0f);
  for (int base = p0; base < p1; base += 64) {
    int myp = base + lane;
    int j = (myp < p1) ? col[myp] : 0;
    float w = (myp < p1) ? dinv[j] : 0.0f;
    int m = p1 - base < 64 ? p1 - base : 64;
#pragma unroll 4
    for (int k = 0; k < m; k += 4) {
      int s = k + sub;               // <= 63 always (k <= 60)
      int jj = __shfl(j, s);
      float ww = __shfl(w, s);       // 0 for tail slots past p1
      float4 hv = H4[(size_t)jj * 16 + cg];
      acc.x = fmaf(hv.x, ww, acc.x);
      acc.y = fmaf(hv.y, ww, acc.y);
      acc.z = fmaf(hv.z, ww, acc.z);
      acc.w = fmaf(hv.w, ww, acc.w);
    }
  }
  // fold the 4 neighbor slots (lanes differing in bits 4,5)
  acc.x += __shfl_xor(acc.x, 16);
  acc.y += __shfl_xor(acc.y, 16);
  acc.z += __shfl_xor(acc.z, 16);
  acc.w += __shfl_xor(acc.w, 16);
  acc.x += __shfl_xor(acc.x, 32);
  acc.y += __shfl_xor(acc.y, 32);
  acc.z += __shfl_xor(acc.z, 32);
  acc.w += __shfl_xor(acc.w, 32);
  float di = dinv[row];
  float d2 = di * di;
  float4 self = H4[(size_t)row * 16 + cg];
  float4 bb = ((const float4*)b)[cg];
  float4 o;
  o.x = fmaf(acc.x, di, fmaf(self.x, d2, bb.x));
  o.y = fmaf(acc.y, di, fmaf(self.y, d2, bb.y));
  o.z = fmaf(acc.z, di, fmaf(self.z, d2, bb.z));
  o.w = fmaf(acc.w, di, fmaf(self.w, d2, bb.w));
  if (sub == 0) ((float4*)OUT)[(size_t)row * 16 + cg] = o;
}

// per-channel sum/sumsq over H [n,64]; 512 blocks grid-stride, LDS reduce
__global__ void bnstats_kernel(const float* __restrict__ H, float* __restrict__ bns, int n) {
  int t = threadIdx.x;
  int ch = t & 63;
  float s = 0.0f, s2 = 0.0f;
  int total = n * 64;
  for (int idx = blockIdx.x * 256 + t; idx < total; idx += 512 * 256) {
    float v = H[idx];
    s += v;
    s2 += v * v;
  }
  __shared__ float ls[256], ls2[256];
  ls[t] = s;
  ls2[t] = s2;
  __syncthreads();
  if (t < 64) {
    s = ls[t] + ls[t + 64] + ls[t + 128] + ls[t + 192];
    s2 = ls2[t] + ls2[t + 64] + ls2[t + 128] + ls2[t + 192];
    atomicAdd(&bns[ch], s);
    atomicAdd(&bns[64 + ch], s2);
  }
}

__global__ void bn_final_kernel(const float* __restrict__ bns, const float* __restrict__ gamma,
                                const float* __restrict__ beta, float* __restrict__ ss, int n) {
  int ch = threadIdx.x;  // 64 threads
  float inv_n = 1.0f / (float)n;
  float mu = bns[ch] * inv_n;
  float var = bns[64 + ch] * inv_n - mu * mu;
  var = fmaxf(var, 0.0f);
  float sc = gamma[ch] * rsqrtf(var + 1e-5f);
  ss[ch] = sc;
  ss[64 + ch] = beta[ch] - mu * sc;
}

// mean-pool from out: 64-row blocks, LDS reduce (sorted batch -> <=2 graphs/block)
__global__ void pool_kernel(const float* __restrict__ O, const int* __restrict__ batch,
                            float* __restrict__ pool, int n) {
  __shared__ float a0[256], a1[256];
  int t = threadIdx.x;
  int ch = t & 63;
  int grp = t >> 6;
  int base = blockIdx.x * 64;
  int first = base < n - 1 ? base : n - 1;
  int lastrow = base + 63 < n - 1 ? base + 63 : n - 1;
  int g0 = batch[first];
  int glast = batch[lastrow];
  float s0 = 0.0f, s1 = 0.0f;
  for (int k = 0; k < 16; ++k) {
    int row = base + grp * 16 + k;
    if (row >= n) break;
    float v = O[(size_t)row * 64 + ch];
    int g = batch[row];
    if (g == g0) s0 += v;
    else if (g == glast) s1 += v;
    else if ((unsigned)g < (unsigned)GGRAPHS) atomicAdd(&pool[g * 64 + ch], v);
  }
  a0[t] = s0;
  a1[t] = s1;
  __syncthreads();
  if (t < 64) {
    float r0 = a0[t] + a0[t + 64] + a0[t + 128] + a0[t + 192];
    if ((unsigned)g0 < (unsigned)GGRAPHS) atomicAdd(&pool[g0 * 64 + t], r0);
    if (glast != g0) {
      float r1 = a1[t] + a1[t + 64] + a1[t + 128] + a1[t + 192];
      if ((unsigned)glast < (unsigned)GGRAPHS) atomicAdd(&pool[glast * 64 + t], r1);
    }
  }
}

__global__ void pool_final_kernel(const float* __restrict__ pool, const int* __restrict__ cnt,
                                  float* __restrict__ out) {
  int idx = blockIdx.x * 256 + threadIdx.x;  // 4096 total
  int g = idx >> 6;
  float c = (float)cnt[g];
  out[idx] = pool[idx] / fmaxf(c, 1.0f);
}

extern "C" void kernel_launch(void* const* d_in, const int* in_sizes, int n_in,
                              void* d_out, int out_size, void* d_ws, size_t ws_size,
                              hipStream_t stream) {
  const float* x = (const float*)d_in[0];
  const int* ei = (const int*)d_in[1];
  const int* batch = (const int*)d_in[2];
  const float* W1 = (const float*)d_in[3];
  const float* b1 = (const float*)d_in[4];
  const float* gamma = (const float*)d_in[5];
  const float* beta = (const float*)d_in[6];
  const float* W2 = (const float*)d_in[7];
  const float* b2 = (const float*)d_in[8];

  const int n = in_sizes[0] / 64;
  const int E = in_sizes[1] / 2;
  const int* srcp = ei;
  const int* dstp = ei + E;

  float* ws = (float*)d_ws;
  size_t nf = (size_t)n * 64;
  float* bufA = ws;                   // h1, then h2'
  float* bufB = ws + nf;              // pre-BN h
  float* dinv = ws + 2 * nf;          // n floats
  int* degi = (int*)(dinv + n);       // n   (zero region starts here)
  int* slot = degi + n;               // n
  float* bns = (float*)(slot + n);    // 128
  float* ss = bns + 128;              // 128
  int* cnti = (int*)(ss + 128);       // 64
  float* pool = (float*)(cnti + 64);  // 4096 (zero region ends here)
  int* rowptr = (int*)(pool + 4096);  // n+1
  int* col = rowptr + n + 1;          // E
  int* bsum = col + E;                // nb+1 (<=257)

  float* out = (float*)d_out;  // FLOAT32 output

  size_t zbytes = (size_t)((char*)(pool + 4096) - (char*)degi);
  hipMemsetAsync(degi, 0, zbytes, stream);

  int blk = 256;
  int gridE = (E + blk - 1) / blk;
  int nb = (n + 255) / 256;           // scan tiles (196 <= 256)
  int gridRows = (n + 3) / 4;
  int gridPool = (n + 63) / 64;

  deg_kernel<<<gridE, blk, 0, stream>>>(dstp, degi, E, n);
  cnt_kernel<<<128, blk, 0, stream>>>(batch, cnti, n);
  scan1_kernel<<<nb, blk, 0, stream>>>(degi, rowptr, bsum, n);
  scan2_kernel<<<1, blk, 0, stream>>>(bsum, nb);
  scan3_kernel<<<nb, blk, 0, stream>>>(degi, rowptr, bsum, dinv, n, nb);
  fill_kernel<<<gridE, blk, 0, stream>>>(srcp, dstp, rowptr, slot, col, E, n);

  mm64_kernel<<<gridRows, blk, 0, stream>>>(x, W1, bufA, n);
  gather_kernel<<<gridRows, blk, 0, stream>>>(rowptr, col, dinv, bufA, b1, bufB, n);
  bnstats_kernel<<<512, blk, 0, stream>>>(bufB, bns, n);
  bn_final_kernel<<<1, 64, 0, stream>>>(bns, gamma, beta, ss, n);
  bn_elu_mm64_kernel<<<gridRows, blk, 0, stream>>>(bufB, W2, ss, bufA, n);
  gather_kernel<<<gridRows, blk, 0, stream>>>(rowptr, col, dinv, bufA, b2, out, n);
  pool_kernel<<<gridPool, blk, 0, stream>>>(out, batch, pool, n);
  pool_final_kernel<<<(GGRAPHS * 64) / blk, blk, 0, stream>>>(pool, cnti, out + nf);
}

// Round 2
// 284.243 us; speedup vs baseline: 1.3013x; 1.1402x over previous
//
#include <hip/hip_runtime.h>

// GCNEncoder: 2x GCNConv(64->64) + BatchNorm + ELU + global_mean_pool
// N=50000, E=800000, D=64, G=64. Inputs f32/int32, output f32.
// R16 451 (1 wave/row gather) -> R17 366.7 (parallel scan) ->
// R18 324.1 (gather float4 4-slot lanes).
// R18 profile: fill_kernel 50us, WRITE_SIZE 55.8MB for 3.2MB of payload
//   (800k scattered 4B writes x 64B sectors, cross-XCD bounce); deg_kernel
//   same random-atomic pattern.
// R19: bucketed counting sort replaces atomic CSR build. Buckets = 256
//   dst-nodes; per-block LDS hist -> scan -> partition (packed src<<8|dlocal,
//   dense per-block chunks) -> per-bucket block builds rowptr/dinv/col with
//   LDS counters only. All col writes stay in the block's own 16KB segment.

constexpr int GGRAPHS = 64;
constexpr int EPB = 8192;  // edges per partition block

// cnt[g] via per-block LDS histogram (batch sorted -> storms stay in LDS)
__global__ void cnt_kernel(const int* __restrict__ batch, int* __restrict__ cnt, int n) {
  __shared__ int h[GGRAPHS];
  int t = threadIdx.x;
  if (t < GGRAPHS) h[t] = 0;
  __syncthreads();
  for (int i = blockIdx.x * 256 + t; i < n; i += gridDim.x * 256) {
    int g = batch[i];
    if ((unsigned)g < (unsigned)GGRAPHS) atomicAdd(&h[g], 1);
  }
  __syncthreads();
  if (t < GGRAPHS && h[t] > 0) atomicAdd(&cnt[t], h[t]);
}

// P1: per-block bucket histogram. hist[b*nblk + blk] = #edges of block blk
// with dst in bucket b (bucket = dst>>8, nbuck <= 256 for n <= 65536).
__global__ void phist_kernel(const int* __restrict__ dst, int* __restrict__ hist,
                             int E, int n, int nblk, int nbuck) {
  __shared__ int h[256];
  int t = threadIdx.x;
  h[t] = 0;
  __syncthreads();
  int e0 = blockIdx.x * EPB;
  int e1 = e0 + EPB < E ? e0 + EPB : E;
  for (int i = e0 + t; i < e1; i += 256) {
    int d = dst[i];
    if ((unsigned)d < (unsigned)n) atomicAdd(&h[d >> 8], 1);
  }
  __syncthreads();
  if (t < nbuck) hist[t * nblk + blockIdx.x] = h[t];
}

// scan pass 1: per-256-tile exclusive scan; out[i]=local excl, bsum[b]=tile total.
__global__ void scan1_kernel(const int* __restrict__ in, int* __restrict__ out,
                             int* __restrict__ bsum, int n) {
  __shared__ int tmp[256];
  int t = threadIdx.x;
  int i = blockIdx.x * 256 + t;
  int v = (i < n) ? in[i] : 0;
  tmp[t] = v;
  __syncthreads();
#pragma unroll
  for (int off = 1; off < 256; off <<= 1) {
    int a = (t >= off) ? tmp[t - off] : 0;
    __syncthreads();
    tmp[t] += a;
    __syncthreads();
  }
  if (i < n) out[i] = tmp[t] - v;  // exclusive
  if (t == 255) bsum[blockIdx.x] = tmp[255];
}

// scan pass 2: 1 block, exclusive scan of bsum[nb] (nb <= 256); bsum[nb] = total.
__global__ void scan2_kernel(int* __restrict__ bsum, int nb) {
  __shared__ int tmp[256];
  int t = threadIdx.x;
  int v = (t < nb) ? bsum[t] : 0;
  tmp[t] = v;
  __syncthreads();
#pragma unroll
  for (int off = 1; off < 256; off <<= 1) {
    int a = (t >= off) ? tmp[t - off] : 0;
    __syncthreads();
    tmp[t] += a;
    __syncthreads();
  }
  if (t < nb) bsum[t] = tmp[t] - v;
  if (t == 255) bsum[nb] = tmp[255];
}

// scan pass 3: data[i] += bsum[tile]; data[S] = grand total.
__global__ void scan_add_kernel(int* __restrict__ data, const int* __restrict__ bsum,
                                int S, int nbt) {
  int i = blockIdx.x * 256 + threadIdx.x;
  if (i < S) data[i] += bsum[blockIdx.x];
  if (i == 0) data[S] = bsum[nbt];
}

// P3: scatter edges into bucket-partitioned array. Each block's chunk within
// each bucket is contiguous (offsets from scanned hist); entries packed as
// (src<<8)|(dst&255). Needs src < 2^24 (n=50000 ok).
__global__ void part_kernel(const int* __restrict__ srcp, const int* __restrict__ dstp,
                            const int* __restrict__ hist, int* __restrict__ part,
                            int E, int n, int nblk, int nbuck) {
  __shared__ int cur[256];
  int t = threadIdx.x;
  if (t < nbuck) cur[t] = hist[t * nblk + blockIdx.x];
  __syncthreads();
  int e0 = blockIdx.x * EPB;
  int e1 = e0 + EPB < E ? e0 + EPB : E;
  for (int i = e0 + t; i < e1; i += 256) {
    int d = dstp[i];
    if ((unsigned)d >= (unsigned)n) continue;
    int s = srcp[i];
    int pos = atomicAdd(&cur[d >> 8], 1);
    part[pos] = (s << 8) | (d & 255);
  }
}

// P4: one block per bucket (256 nodes). LDS degree count -> LDS scan ->
// coalesced rowptr/dinv write -> place col via LDS slot cursors. All col
// writes land in this bucket's contiguous [base,end) segment.
__global__ void csr_kernel(const int* __restrict__ part, const int* __restrict__ hist,
                           int* __restrict__ rowptr, float* __restrict__ dinv,
                           int* __restrict__ col, int n, int nblk, int nbuck) {
  __shared__ int degL[256], scn[256], cur[256];
  int t = threadIdx.x;
  int b = blockIdx.x;
  degL[t] = 0;
  cur[t] = 0;
  __syncthreads();
  int base = hist[b * nblk];
  int end = hist[(b + 1) * nblk];  // hist[S] = total for last bucket
  for (int i = base + t; i < end; i += 256) atomicAdd(&degL[part[i] & 255], 1);
  __syncthreads();
  int dv = degL[t];
  scn[t] = dv;
  __syncthreads();
#pragma unroll
  for (int off = 1; off < 256; off <<= 1) {
    int a = (t >= off) ? scn[t - off] : 0;
    __syncthreads();
    scn[t] += a;
    __syncthreads();
  }
  int excl = scn[t] - dv;
  int node = (b << 8) + t;
  if (node < n) {
    rowptr[node] = base + excl;
    dinv[node] = rsqrtf((float)dv + 1.0f);
  }
  if (b == nbuck - 1 && t == 0) rowptr[n] = end;
  scn[t] = excl;
  __syncthreads();
  for (int i = base + t; i < end; i += 256) {
    int u = part[i];
    int d = u & 255;
    int k = atomicAdd(&cur[d], 1);
    col[base + scn[d] + k] = u >> 8;
  }
}

// Y[n,64] = X[n,64] @ W[64,64]; block = 4 rows x 64 cols
__global__ void mm64_kernel(const float* __restrict__ X, const float* __restrict__ W,
                            float* __restrict__ Y, int n) {
  __shared__ float Ws[64][64];
  __shared__ float xs[4][64];
  int tid = threadIdx.x;
  for (int i = tid; i < 64 * 64; i += 256) Ws[i >> 6][i & 63] = W[i];
  int rr = tid >> 6, c = tid & 63;
  int row = blockIdx.x * 4 + rr;
  xs[rr][c] = (row < n) ? X[row * 64 + c] : 0.0f;
  __syncthreads();
  float acc = 0.0f;
#pragma unroll
  for (int k = 0; k < 64; ++k) acc = fmaf(xs[rr][k], Ws[k][c], acc);
  if (row < n) Y[row * 64 + c] = acc;
}

// BN affine + ELU on X rows, then @W
__global__ void bn_elu_mm64_kernel(const float* __restrict__ X, const float* __restrict__ W,
                                   const float* __restrict__ ss, float* __restrict__ Y, int n) {
  __shared__ float Ws[64][64];
  __shared__ float xs[4][64];
  int tid = threadIdx.x;
  for (int i = tid; i < 64 * 64; i += 256) Ws[i >> 6][i & 63] = W[i];
  int rr = tid >> 6, c = tid & 63;
  int row = blockIdx.x * 4 + rr;
  float v = 0.0f;
  if (row < n) {
    v = X[row * 64 + c] * ss[c] + ss[64 + c];
    v = v > 0.0f ? v : expm1f(v);
  }
  xs[rr][c] = v;
  __syncthreads();
  float acc = 0.0f;
#pragma unroll
  for (int k = 0; k < 64; ++k) acc = fmaf(xs[rr][k], Ws[k][c], acc);
  if (row < n) Y[row * 64 + c] = acc;
}

// CSR gather, 1 wave per row. Lanes = 4 neighbor-slots x 16 channel-quads:
// each lane float4-loads 4 channels of one of 4 concurrent neighbor rows.
__global__ void gather_kernel(const int* __restrict__ rowptr, const int* __restrict__ col,
                              const float* __restrict__ dinv, const float* __restrict__ H,
                              const float* __restrict__ b, float* __restrict__ OUT, int n) {
  int wave = threadIdx.x >> 6;
  int lane = threadIdx.x & 63;
  int row = blockIdx.x * 4 + wave;
  if (row >= n) return;
  int sub = lane >> 4;   // neighbor slot 0..3
  int cg = lane & 15;    // channel quad: channels 4*cg .. 4*cg+3
  int p0 = rowptr[row], p1 = rowptr[row + 1];
  const float4* __restrict__ H4 = (const float4*)H;
  float4 acc = make_float4(0.0f, 0.0f, 0.0f, 0.0f);
  for (int base = p0; base < p1; base += 64) {
    int myp = base + lane;
    int j = (myp < p1) ? col[myp] : 0;
    float w = (myp < p1) ? dinv[j] : 0.0f;
    int m = p1 - base < 64 ? p1 - base : 64;
#pragma unroll 4
    for (int k = 0; k < m; k += 4) {
      int s = k + sub;               // <= 63 always (k <= 60)
      int jj = __shfl(j, s);
      float ww = __shfl(w, s);       // 0 for tail slots past p1
      float4 hv = H4[(size_t)jj * 16 + cg];
      acc.x = fmaf(hv.x, ww, acc.x);
      acc.y = fmaf(hv.y, ww, acc.y);
      acc.z = fmaf(hv.z, ww, acc.z);
      acc.w = fmaf(hv.w, ww, acc.w);
    }
  }
  acc.x += __shfl_xor(acc.x, 16);
  acc.y += __shfl_xor(acc.y, 16);
  acc.z += __shfl_xor(acc.z, 16);
  acc.w += __shfl_xor(acc.w, 16);
  acc.x += __shfl_xor(acc.x, 32);
  acc.y += __shfl_xor(acc.y, 32);
  acc.z += __shfl_xor(acc.z, 32);
  acc.w += __shfl_xor(acc.w, 32);
  float di = dinv[row];
  float d2 = di * di;
  float4 self = H4[(size_t)row * 16 + cg];
  float4 bb = ((const float4*)b)[cg];
  float4 o;
  o.x = fmaf(acc.x, di, fmaf(self.x, d2, bb.x));
  o.y = fmaf(acc.y, di, fmaf(self.y, d2, bb.y));
  o.z = fmaf(acc.z, di, fmaf(self.z, d2, bb.z));
  o.w = fmaf(acc.w, di, fmaf(self.w, d2, bb.w));
  if (sub == 0) ((float4*)OUT)[(size_t)row * 16 + cg] = o;
}

// per-channel sum/sumsq over H [n,64]; 512 blocks grid-stride, LDS reduce
__global__ void bnstats_kernel(const float* __restrict__ H, float* __restrict__ bns, int n) {
  int t = threadIdx.x;
  int ch = t & 63;
  float s = 0.0f, s2 = 0.0f;
  int total = n * 64;
  for (int idx = blockIdx.x * 256 + t; idx < total; idx += 512 * 256) {
    float v = H[idx];
    s += v;
    s2 += v * v;
  }
  __shared__ float ls[256], ls2[256];
  ls[t] = s;
  ls2[t] = s2;
  __syncthreads();
  if (t < 64) {
    s = ls[t] + ls[t + 64] + ls[t + 128] + ls[t + 192];
    s2 = ls2[t] + ls2[t + 64] + ls2[t + 128] + ls2[t + 192];
    atomicAdd(&bns[ch], s);
    atomicAdd(&bns[64 + ch], s2);
  }
}

__global__ void bn_final_kernel(const float* __restrict__ bns, const float* __restrict__ gamma,
                                const float* __restrict__ beta, float* __restrict__ ss, int n) {
  int ch = threadIdx.x;  // 64 threads
  float inv_n = 1.0f / (float)n;
  float mu = bns[ch] * inv_n;
  float var = bns[64 + ch] * inv_n - mu * mu;
  var = fmaxf(var, 0.0f);
  float sc = gamma[ch] * rsqrtf(var + 1e-5f);
  ss[ch] = sc;
  ss[64 + ch] = beta[ch] - mu * sc;
}

// mean-pool from out: 64-row blocks, LDS reduce (sorted batch -> <=2 graphs/block)
__global__ void pool_kernel(const float* __restrict__ O, const int* __restrict__ batch,
                            float* __restrict__ pool, int n) {
  __shared__ float a0[256], a1[256];
  int t = threadIdx.x;
  int ch = t & 63;
  int grp = t >> 6;
  int base = blockIdx.x * 64;
  int first = base < n - 1 ? base : n - 1;
  int lastrow = base + 63 < n - 1 ? base + 63 : n - 1;
  int g0 = batch[first];
  int glast = batch[lastrow];
  float s0 = 0.0f, s1 = 0.0f;
  for (int k = 0; k < 16; ++k) {
    int row = base + grp * 16 + k;
    if (row >= n) break;
    float v = O[(size_t)row * 64 + ch];
    int g = batch[row];
    if (g == g0) s0 += v;
    else if (g == glast) s1 += v;
    else if ((unsigned)g < (unsigned)GGRAPHS) atomicAdd(&pool[g * 64 + ch], v);
  }
  a0[t] = s0;
  a1[t] = s1;
  __syncthreads();
  if (t < 64) {
    float r0 = a0[t] + a0[t + 64] + a0[t + 128] + a0[t + 192];
    if ((unsigned)g0 < (unsigned)GGRAPHS) atomicAdd(&pool[g0 * 64 + t], r0);
    if (glast != g0) {
      float r1 = a1[t] + a1[t + 64] + a1[t + 128] + a1[t + 192];
      if ((unsigned)glast < (unsigned)GGRAPHS) atomicAdd(&pool[glast * 64 + t], r1);
    }
  }
}

__global__ void pool_final_kernel(const float* __restrict__ pool, const int* __restrict__ cnt,
                                  float* __restrict__ out) {
  int idx = blockIdx.x * 256 + threadIdx.x;  // 4096 total
  int g = idx >> 6;
  float c = (float)cnt[g];
  out[idx] = pool[idx] / fmaxf(c, 1.0f);
}

extern "C" void kernel_launch(void* const* d_in, const int* in_sizes, int n_in,
                              void* d_out, int out_size, void* d_ws, size_t ws_size,
                              hipStream_t stream) {
  const float* x = (const float*)d_in[0];
  const int* ei = (const int*)d_in[1];
  const int* batch = (const int*)d_in[2];
  const float* W1 = (const float*)d_in[3];
  const float* b1 = (const float*)d_in[4];
  const float* gamma = (const float*)d_in[5];
  const float* beta = (const float*)d_in[6];
  const float* W2 = (const float*)d_in[7];
  const float* b2 = (const float*)d_in[8];

  const int n = in_sizes[0] / 64;
  const int E = in_sizes[1] / 2;
  const int* srcp = ei;
  const int* dstp = ei + E;

  float* ws = (float*)d_ws;
  size_t nf = (size_t)n * 64;
  float* bufA = ws;                   // h1, then h2' (aliases part/hist in preproc)
  float* bufB = ws + nf;              // pre-BN h
  float* dinv = ws + 2 * nf;          // n floats
  float* bns = dinv + n;              // 128 (zero region starts here)
  float* ss = bns + 128;              // 128
  int* cnti = (int*)(ss + 128);       // 64
  float* pool = (float*)(cnti + 64);  // 4096 (zero region ends here)
  int* rowptr = (int*)(pool + 4096);  // n+1
  int* col = rowptr + n + 1;          // E
  int* bsum = col + E;                // <=257

  // preprocessing scratch aliased into bufA (free until mm64)
  int* part = (int*)bufA;             // E packed edges
  int* hist = part + E;               // S+1

  float* out = (float*)d_out;  // FLOAT32 output

  size_t zbytes = (size_t)((char*)(pool + 4096) - (char*)bns);
  hipMemsetAsync(bns, 0, zbytes, stream);

  int blk = 256;
  int nblkP = (E + EPB - 1) / EPB;    // 98 partition blocks
  int nbuck = (n + 255) >> 8;         // 196 buckets (needs n <= 65536)
  int S = nbuck * nblkP;              // 19208 counters
  int nbt = (S + 255) / 256;          // 76 scan tiles (<= 256)
  int gridRows = (n + 3) / 4;
  int gridPool = (n + 63) / 64;

  phist_kernel<<<nblkP, blk, 0, stream>>>(dstp, hist, E, n, nblkP, nbuck);
  cnt_kernel<<<128, blk, 0, stream>>>(batch, cnti, n);
  scan1_kernel<<<nbt, blk, 0, stream>>>(hist, hist, bsum, S);
  scan2_kernel<<<1, blk, 0, stream>>>(bsum, nbt);
  scan_add_kernel<<<nbt, blk, 0, stream>>>(hist, bsum, S, nbt);
  part_kernel<<<nblkP, blk, 0, stream>>>(srcp, dstp, hist, part, E, n, nblkP, nbuck);
  csr_kernel<<<nbuck, blk, 0, stream>>>(part, hist, rowptr, dinv, col, n, nblkP, nbuck);

  mm64_kernel<<<gridRows, blk, 0, stream>>>(x, W1, bufA, n);
  gather_kernel<<<gridRows, blk, 0, stream>>>(rowptr, col, dinv, bufA, b1, bufB, n);
  bnstats_kernel<<<512, blk, 0, stream>>>(bufB, bns, n);
  bn_final_kernel<<<1, 64, 0, stream>>>(bns, gamma, beta, ss, n);
  bn_elu_mm64_kernel<<<gridRows, blk, 0, stream>>>(bufB, W2, ss, bufA, n);
  gather_kernel<<<gridRows, blk, 0, stream>>>(rowptr, col, dinv, bufA, b2, out, n);
  pool_kernel<<<gridPool, blk, 0, stream>>>(out, batch, pool, n);
  pool_final_kernel<<<(GGRAPHS * 64) / blk, blk, 0, stream>>>(pool, cnti, out + nf);
}